// Round 2
// baseline (622.470 us; speedup 1.0000x reference)
//
#include <hip/hip_runtime.h>

// GGCARAFE: gradient-guided CARAFE upsample, B=8, C=256, H=W=64, K=3, S=2
// ws layout (floats):
//   w1t  [256][64]             @ 0         (16384)   w1t[c*64+j]   = w1[j][c]
//   w2t2 [4][64][3][3][9]      @ 16384     (20736)   [pq][j][dy][dx][kk] = w2[(kk*4+pq)*576 + j*9+dy*3+dx]
//   mean [B][H][W]             @ 37120     (32768)
//   comp [B][64][H][W]         @ 69888     (2097152)
//   mask [B][H][W][4][9]       @ 2167040   (1179648)
// total 3,346,688 floats = 13.4 MB

#define W1T_OFF   0
#define W2T_OFF   16384
#define MEAN_OFF  37120
#define COMP_OFF  69888
#define MASK_OFF  2167040

__global__ __launch_bounds__(256) void k_setup(const float* __restrict__ w1,
                                               const float* __restrict__ w2,
                                               float* __restrict__ ws) {
    float* w1t = ws + W1T_OFF;
    float* w2t = ws + W2T_OFF;
    int t = threadIdx.x;
    // w1: [64][256] (OIHW 1x1) -> w1t[c][j]
    for (int i = t; i < 64 * 256; i += 256) {
        int c = i >> 6, j = i & 63;
        w1t[i] = w1[j * 256 + c];
    }
    // w2: [36][64][3][3] -> w2t2[pq][j][dy][dx][kk]
    for (int i = t; i < 4 * 64 * 3 * 3 * 9; i += 256) {
        int kk = i % 9;
        int dx = (i / 9) % 3;
        int dy = (i / 27) % 3;
        int j  = (i / 81) % 64;
        int pq = i / 5184;
        w2t[i] = w2[(kk * 4 + pq) * 576 + j * 9 + dy * 3 + dx];
    }
}

// comp[b][j][hw] = b1[j] + sum_c w1[j][c] * x[b][c][hw];  mean[b][hw] = avg_c x
// grid 512: jg = blockIdx>>7 (4 groups of 16 j), pix = (blockIdx&127)*256 + tid
__global__ __launch_bounds__(256) void k_comp(const float* __restrict__ x,
                                              const float* __restrict__ b1,
                                              float* __restrict__ ws) {
    const float* w1t = ws + W1T_OFF;
    float* mean = ws + MEAN_OFF;
    float* comp = ws + COMP_OFF;
    int jg = blockIdx.x >> 7;                          // uniform
    int pix = ((blockIdx.x & 127) << 8) + threadIdx.x; // 0..32767
    int b = pix >> 12, hw = pix & 4095;
    const float* xp = x + (size_t)b * 256 * 4096 + hw;
    float acc[16];
#pragma unroll
    for (int jj = 0; jj < 16; jj++) acc[jj] = b1[jg * 16 + jj];
    float msum = 0.f;
    for (int c = 0; c < 256; c += 8) {
        float xv[8];
#pragma unroll
        for (int u = 0; u < 8; u++) xv[u] = xp[(size_t)(c + u) * 4096];
#pragma unroll
        for (int u = 0; u < 8; u++) {
            msum += xv[u];
            const float* wp = w1t + (c + u) * 64 + jg * 16;   // uniform -> s_load
#pragma unroll
            for (int jj = 0; jj < 16; jj++) acc[jj] += wp[jj] * xv[u];
        }
    }
    float* cb = comp + (size_t)b * 64 * 4096 + hw;
#pragma unroll
    for (int jj = 0; jj < 16; jj++) cb[(size_t)(jg * 16 + jj) * 4096] = acc[jj];
    if (jg == 0) mean[pix] = msum * (1.f / 256.f);
}

// 3x3 conv on comp + gradient guidance + softmax -> mask
// grid 512 = (b,h); 256 threads = 4 pq-waves x 64 w. LDS-staged comp in 8-j chunks.
#define JC 8
__global__ __launch_bounds__(256) void k_mask(const float* __restrict__ b2,
                                              float* __restrict__ ws) {
    const float* w2t = ws + W2T_OFF;
    const float* mean = ws + MEAN_OFF;
    const float* comp = ws + COMP_OFF;
    float* mask = ws + MASK_OFF;

    __shared__ float smem[JC * 3 * 64];

    int bh = blockIdx.x;
    int b = bh >> 6, h = bh & 63;
    int t = threadIdx.x;
    int pq = t >> 6;          // wave-uniform (one pq per wave)
    int w = t & 63;

    float acc[9];
#pragma unroll
    for (int kk = 0; kk < 9; kk++) acc[kk] = b2[kk * 4 + pq];

    const float* cb = comp + (size_t)b * 64 * 4096;

    for (int jc = 0; jc < 64; jc += JC) {
        __syncthreads();
        // stage comp[jc..jc+8][h-1..h+1][0..63] with zero padding for y OOB
#pragma unroll
        for (int r = 0; r < JC * 3 * 64 / 256; r++) {
            int idx = t + r * 256;
            int jj  = idx / 192;
            int rem = idx - jj * 192;
            int row = rem >> 6, wl = rem & 63;
            int y = h + row - 1;
            float v = 0.f;
            if ((unsigned)y < 64u) v = cb[(size_t)(jc + jj) * 4096 + y * 64 + wl];
            smem[idx] = v;
        }
        __syncthreads();

#pragma unroll
        for (int jj = 0; jj < JC; jj++) {
#pragma unroll
            for (int dy = 0; dy < 3; dy++) {
                const float* srow = smem + jj * 192 + dy * 64;
                float c1 = srow[w];
                float c0 = (w > 0)  ? srow[w - 1] : 0.f;
                float c2 = (w < 63) ? srow[w + 1] : 0.f;
                // 27 contiguous wave-uniform weights -> s_load
                const float* wb = w2t + (size_t)(((pq * 64 + jc + jj) * 3 + dy) * 27);
#pragma unroll
                for (int kk = 0; kk < 9; kk++)
                    acc[kk] += wb[kk] * c0 + wb[9 + kk] * c1 + wb[18 + kk] * c2;
            }
        }
    }

    // gradient guidance from mean patch
    float mc = mean[(b * 64 + h) * 64 + w];
    float v[9], mx = -1e30f;
#pragma unroll
    for (int kk = 0; kk < 9; kk++) {
        int y = h + kk / 3 - 1, xw = w + kk % 3 - 1;
        float mv = ((unsigned)y < 64u && (unsigned)xw < 64u)
                       ? mean[(b * 64 + y) * 64 + xw] : 0.f;
        float d = mv - mc;
        float g = 1.f / (d * d + 0.2f);
        v[kk] = g * acc[kk];
        mx = fmaxf(mx, v[kk]);
    }
    float s = 0.f;
#pragma unroll
    for (int kk = 0; kk < 9; kk++) {
        v[kk] = __expf(v[kk] - mx);
        s += v[kk];
    }
    float inv = 1.f / s;
    float* mout = mask + ((size_t)((b * 64 + h) * 64 + w)) * 36 + pq * 9;
#pragma unroll
    for (int kk = 0; kk < 9; kk++) mout[kk] = v[kk] * inv;
}

// out[b][c][2h+p][2w+q] = sum_kk x[b][c][h+dy-1][w+dx-1] * mask[b][h][w][p*2+q][kk]
// grid 2048 = (b,h,cq); threads: ow = t&127, cslot = t>>7; c = cq*64 + cslot + 2i
__global__ __launch_bounds__(256) void k_out(const float* __restrict__ x,
                                             const float* __restrict__ ws,
                                             float* __restrict__ out) {
    const float* mask = ws + MASK_OFF;
    int bh = blockIdx.x >> 2, cq = blockIdx.x & 3;
    int b = bh >> 6, h = bh & 63;
    int t = threadIdx.x;
    int ow = t & 127, cslot = t >> 7;
    int w = ow >> 1, q = ow & 1;

    const float* mrow = mask + (size_t)((b * 64 + h) * 64 + w) * 36;
    float m0[9], m1[9];
#pragma unroll
    for (int kk = 0; kk < 9; kk++) {
        m0[kk] = mrow[q * 9 + kk];        // p=0 -> pq=q
        m1[kk] = mrow[(2 + q) * 9 + kk];  // p=1 -> pq=2+q
    }

    for (int c = cq * 64 + cslot; c < (cq + 1) * 64; c += 2) {
        const float* xb = x + (size_t)(b * 256 + c) * 4096;
        float p[3][3];
#pragma unroll
        for (int dy = 0; dy < 3; dy++) {
            int y = h + dy - 1;
            bool yok = (unsigned)y < 64u;
#pragma unroll
            for (int dx = 0; dx < 3; dx++) {
                int xx = w + dx - 1;
                p[dy][dx] = (yok && (unsigned)xx < 64u) ? xb[y * 64 + xx] : 0.f;
            }
        }
        float o0 = 0.f, o1 = 0.f;
#pragma unroll
        for (int kk = 0; kk < 9; kk++) {
            float pv = p[kk / 3][kk % 3];
            o0 += pv * m0[kk];
            o1 += pv * m1[kk];
        }
        float* ob = out + ((size_t)(b * 256 + c) * 128 + 2 * h) * 128 + ow;
        ob[0] = o0;     // p=0 row
        ob[128] = o1;   // p=1 row
    }
}

extern "C" void kernel_launch(void* const* d_in, const int* in_sizes, int n_in,
                              void* d_out, int out_size, void* d_ws, size_t ws_size,
                              hipStream_t stream) {
    const float* x  = (const float*)d_in[0];
    const float* w1 = (const float*)d_in[1];
    const float* b1 = (const float*)d_in[2];
    const float* w2 = (const float*)d_in[3];
    const float* b2 = (const float*)d_in[4];
    float* out = (float*)d_out;
    float* ws  = (float*)d_ws;

    k_setup<<<1, 256, 0, stream>>>(w1, w2, ws);
    k_comp<<<512, 256, 0, stream>>>(x, b1, ws);
    k_mask<<<512, 256, 0, stream>>>(b2, ws);
    k_out<<<2048, 256, 0, stream>>>(x, ws, out);
}

// Round 4
// 242.599 us; speedup vs baseline: 2.5658x; 2.5658x over previous
//
#include <hip/hip_runtime.h>

// GGCARAFE: gradient-guided CARAFE upsample, B=8, C=256, H=W=64, K=3, S=2
// ws layout (floats):
//   w1t  [256][64]             @ 0         (16384)   w1t[c*64+j]   = w1[j][c]
//   w2t2 [4][64][3][3][9]      @ 16384     (20736)   [pq][j][dy][dx][kk] = w2[(kk*4+pq)*576 + j*9+dy*3+dx]
//   mean [B][H][W]             @ 37120     (32768)
//   comp [B][64][H][W]         @ 69888     (2097152)
//   mask [B][H][W][4][9]       @ 2167040   (1179648)
// total 3,346,688 floats = 13.4 MB

#define W1T_OFF   0
#define W2T_OFF   16384
#define MEAN_OFF  37120
#define COMP_OFF  69888
#define MASK_OFF  2167040

__global__ __launch_bounds__(256) void k_setup(const float* __restrict__ w1,
                                               const float* __restrict__ w2,
                                               float* __restrict__ ws) {
    float* w1t = ws + W1T_OFF;
    float* w2t = ws + W2T_OFF;
    int t = threadIdx.x;
    // w1: [64][256] (OIHW 1x1) -> w1t[c][j]
    for (int i = t; i < 64 * 256; i += 256) {
        int c = i >> 6, j = i & 63;
        w1t[i] = w1[j * 256 + c];
    }
    // w2: [36][64][3][3] -> w2t2[pq][j][dy][dx][kk]
    for (int i = t; i < 4 * 64 * 3 * 3 * 9; i += 256) {
        int kk = i % 9;
        int dx = (i / 9) % 3;
        int dy = (i / 27) % 3;
        int j  = (i / 81) % 64;
        int pq = i / 5184;
        w2t[i] = w2[(kk * 4 + pq) * 576 + j * 9 + dy * 3 + dx];
    }
}

// comp[b][j][hw] = b1[j] + sum_c w1[j][c] * x[b][c][hw];  mean[b][hw] = avg_c x
// grid 512: jg = blockIdx>>7 (4 groups of 16 j), pix = (blockIdx&127)*256 + tid
__global__ __launch_bounds__(256) void k_comp(const float* __restrict__ x,
                                              const float* __restrict__ b1,
                                              float* __restrict__ ws) {
    const float* w1t = ws + W1T_OFF;
    float* mean = ws + MEAN_OFF;
    float* comp = ws + COMP_OFF;
    int jg = blockIdx.x >> 7;                          // uniform
    int pix = ((blockIdx.x & 127) << 8) + threadIdx.x; // 0..32767
    int b = pix >> 12, hw = pix & 4095;
    const float* xp = x + (size_t)b * 256 * 4096 + hw;
    float acc[16];
#pragma unroll
    for (int jj = 0; jj < 16; jj++) acc[jj] = b1[jg * 16 + jj];
    float msum = 0.f;
    for (int c = 0; c < 256; c += 8) {
        float xv[8];
#pragma unroll
        for (int u = 0; u < 8; u++) xv[u] = xp[(size_t)(c + u) * 4096];
#pragma unroll
        for (int u = 0; u < 8; u++) {
            msum += xv[u];
            const float* wp = w1t + (c + u) * 64 + jg * 16;   // uniform -> s_load
#pragma unroll
            for (int jj = 0; jj < 16; jj++) acc[jj] += wp[jj] * xv[u];
        }
    }
    float* cb = comp + (size_t)b * 64 * 4096 + hw;
#pragma unroll
    for (int jj = 0; jj < 16; jj++) cb[(size_t)(jg * 16 + jj) * 4096] = acc[jj];
    if (jg == 0) mean[pix] = msum * (1.f / 256.f);
}

// 3x3 conv on comp + gradient guidance + softmax -> mask
// grid 512 = (b,h); 256 threads = 4 pq-waves x 64 w. LDS-staged comp in 8-j chunks.
// pq is forced into an SGPR via readfirstlane so ALL weight/bias loads are
// scalar (s_load) — R2 lesson: threadIdx-derived index ⇒ vector loads ⇒
// 256 VGPR + 1.1 GB scratch spill.
// R3 lesson: per-pq stride is 64*3*3*9 = 5184 floats (NOT 64*27).
#define JC 8
__global__ __launch_bounds__(256) void k_mask(const float* __restrict__ b2,
                                              float* __restrict__ ws) {
    const float* w2t = ws + W2T_OFF;
    const float* mean = ws + MEAN_OFF;
    const float* comp = ws + COMP_OFF;
    float* mask = ws + MASK_OFF;

    __shared__ float smem[JC * 3 * 64];

    int bh = blockIdx.x;
    int b = bh >> 6, h = bh & 63;
    int t = threadIdx.x;
    int pq = __builtin_amdgcn_readfirstlane(t >> 6);   // wave-uniform -> SGPR
    int w = t & 63;

    const float* wpq = w2t + (size_t)pq * 5184;        // scalar base, [j][dy][dx][kk]

    float acc[9];
#pragma unroll
    for (int kk = 0; kk < 9; kk++) acc[kk] = b2[kk * 4 + pq];

    const float* cb = comp + (size_t)b * 64 * 4096;

    for (int jc = 0; jc < 64; jc += JC) {
        __syncthreads();
        // stage comp[jc..jc+8][h-1..h+1][0..63] with zero padding for y OOB
#pragma unroll
        for (int r = 0; r < JC * 3 * 64 / 256; r++) {
            int idx = t + r * 256;
            int jj  = idx / 192;
            int rem = idx - jj * 192;
            int row = rem >> 6, wl = rem & 63;
            int y = h + row - 1;
            float v = 0.f;
            if ((unsigned)y < 64u) v = cb[(size_t)(jc + jj) * 4096 + y * 64 + wl];
            smem[idx] = v;
        }
        __syncthreads();

#pragma unroll
        for (int jj = 0; jj < JC; jj++) {
#pragma unroll
            for (int dy = 0; dy < 3; dy++) {
                const float* srow = smem + jj * 192 + dy * 64;
                float c1 = srow[w];
                float c0 = (w > 0)  ? srow[w - 1] : 0.f;
                float c2 = (w < 63) ? srow[w + 1] : 0.f;
                // 27 contiguous scalar weights (SGPR base + const offset)
                const float* wb = wpq + ((jc + jj) * 3 + dy) * 27;
#pragma unroll
                for (int kk = 0; kk < 9; kk++)
                    acc[kk] += wb[kk] * c0 + wb[9 + kk] * c1 + wb[18 + kk] * c2;
            }
        }
    }

    // gradient guidance from mean patch
    float mc = mean[(b * 64 + h) * 64 + w];
    float v[9], mx = -1e30f;
#pragma unroll
    for (int kk = 0; kk < 9; kk++) {
        int y = h + kk / 3 - 1, xw = w + kk % 3 - 1;
        float mv = ((unsigned)y < 64u && (unsigned)xw < 64u)
                       ? mean[(b * 64 + y) * 64 + xw] : 0.f;
        float d = mv - mc;
        float g = 1.f / (d * d + 0.2f);
        v[kk] = g * acc[kk];
        mx = fmaxf(mx, v[kk]);
    }
    float s = 0.f;
#pragma unroll
    for (int kk = 0; kk < 9; kk++) {
        v[kk] = __expf(v[kk] - mx);
        s += v[kk];
    }
    float inv = 1.f / s;
    float* mout = mask + ((size_t)((b * 64 + h) * 64 + w)) * 36 + pq * 9;
#pragma unroll
    for (int kk = 0; kk < 9; kk++) mout[kk] = v[kk] * inv;
}

// out[b][c][2h+p][2w+q] = sum_kk x[b][c][h+dy-1][w+dx-1] * mask[b][h][w][p*2+q][kk]
// grid 2048 = (b,h,cq); threads: ow = t&127, cslot = t>>7; c = cq*64 + cslot + 2i
__global__ __launch_bounds__(256) void k_out(const float* __restrict__ x,
                                             const float* __restrict__ ws,
                                             float* __restrict__ out) {
    const float* mask = ws + MASK_OFF;
    int bh = blockIdx.x >> 2, cq = blockIdx.x & 3;
    int b = bh >> 6, h = bh & 63;
    int t = threadIdx.x;
    int ow = t & 127, cslot = t >> 7;
    int w = ow >> 1, q = ow & 1;

    const float* mrow = mask + (size_t)((b * 64 + h) * 64 + w) * 36;
    float m0[9], m1[9];
#pragma unroll
    for (int kk = 0; kk < 9; kk++) {
        m0[kk] = mrow[q * 9 + kk];        // p=0 -> pq=q
        m1[kk] = mrow[(2 + q) * 9 + kk];  // p=1 -> pq=2+q
    }

    for (int c = cq * 64 + cslot; c < (cq + 1) * 64; c += 2) {
        const float* xb = x + (size_t)(b * 256 + c) * 4096;
        float p[3][3];
#pragma unroll
        for (int dy = 0; dy < 3; dy++) {
            int y = h + dy - 1;
            bool yok = (unsigned)y < 64u;
#pragma unroll
            for (int dx = 0; dx < 3; dx++) {
                int xx = w + dx - 1;
                p[dy][dx] = (yok && (unsigned)xx < 64u) ? xb[y * 64 + xx] : 0.f;
            }
        }
        float o0 = 0.f, o1 = 0.f;
#pragma unroll
        for (int kk = 0; kk < 9; kk++) {
            float pv = p[kk / 3][kk % 3];
            o0 += pv * m0[kk];
            o1 += pv * m1[kk];
        }
        float* ob = out + ((size_t)(b * 256 + c) * 128 + 2 * h) * 128 + ow;
        ob[0] = o0;     // p=0 row
        ob[128] = o1;   // p=1 row
    }
}

extern "C" void kernel_launch(void* const* d_in, const int* in_sizes, int n_in,
                              void* d_out, int out_size, void* d_ws, size_t ws_size,
                              hipStream_t stream) {
    const float* x  = (const float*)d_in[0];
    const float* w1 = (const float*)d_in[1];
    const float* b1 = (const float*)d_in[2];
    const float* w2 = (const float*)d_in[3];
    const float* b2 = (const float*)d_in[4];
    float* out = (float*)d_out;
    float* ws  = (float*)d_ws;

    k_setup<<<1, 256, 0, stream>>>(w1, w2, ws);
    k_comp<<<512, 256, 0, stream>>>(x, b1, ws);
    k_mask<<<512, 256, 0, stream>>>(b2, ws);
    k_out<<<2048, 256, 0, stream>>>(x, ws, out);
}

// Round 5
// 96.395 us; speedup vs baseline: 6.4575x; 2.5167x over previous
//
#include <hip/hip_runtime.h>

// GGCARAFE: gradient-guided CARAFE upsample, B=8, C=256, H=W=64, K=3, S=2
// R5: mask conv (3x3, 36 out, K=576) rewritten as bf16 MFMA GEMM.
// ws layout (float indices):
//   w1t   [256][64] f32         @ 0        (16384)   w1t[c*64+j] = w1[j][c]
//   mean  [B][H][W] f32         @ 16384    (32768)
//   mask  [B][H][W][4][9] f32   @ 49152    (1179648)
//   w2b   [48][576] bf16        @ 1228800  (13824 f32-equiv)  w2b[o][s*64+j] = w2[o][j][dy][dx], o>=36 -> 0
//   comp_p[8][66][66][64] bf16  @ 1242624  (1115136 f32-equiv) zero ring, interior = comp
// total 2,357,760 floats = 9.43 MB (< previous 13.4 MB)

#define W1T_OFF   0
#define MEAN_OFF  16384
#define MASK_OFF  49152
#define W2B_OFF   1228800
#define CPP_OFF   1242624

typedef __attribute__((ext_vector_type(8))) short bf8;            // 8 bf16 = 16B
typedef __attribute__((ext_vector_type(8))) unsigned short us8;   // 16B store
typedef __attribute__((ext_vector_type(4))) float f4;

static __device__ inline unsigned short f2bf(float f) {
    unsigned u = __float_as_uint(f);
    unsigned r = u + 0x7FFFu + ((u >> 16) & 1u);   // RNE
    return (unsigned short)(r >> 16);
}

// zero comp_p (padding ring must be 0; ws is poisoned 0xAA before timing)
// 8*66*66*64 bf16 = 4,460,544 B = 278,784 x 16B; grid 1089 x 256 exact.
__global__ __launch_bounds__(256) void k_zero(float* __restrict__ ws) {
    uint4* p = (uint4*)(ws + CPP_OFF);
    p[blockIdx.x * 256 + threadIdx.x] = uint4{0, 0, 0, 0};
}

__global__ __launch_bounds__(256) void k_setup(const float* __restrict__ w1,
                                               const float* __restrict__ w2,
                                               float* __restrict__ ws) {
    float* w1t = ws + W1T_OFF;
    unsigned short* w2b = (unsigned short*)(ws + W2B_OFF);
    int gid = blockIdx.x * 256 + threadIdx.x;
    int stride = gridDim.x * 256;
    // w1: [64][256] -> w1t[c][j]
    for (int i = gid; i < 64 * 256; i += stride) {
        int c = i >> 6, j = i & 63;
        w1t[i] = w1[j * 256 + c];
    }
    // w2: [36][64][3][3] -> w2b[o][s*64+j] bf16 (o padded to 48 with 0)
    for (int i = gid; i < 48 * 576; i += stride) {
        int o = i / 576, k = i % 576;
        int s = k >> 6, j = k & 63;
        w2b[i] = (o < 36) ? f2bf(w2[o * 576 + j * 9 + s]) : (unsigned short)0;
    }
}

// comp_p[b][h+1][w+1][j] = bf16(b1[j] + sum_c w1[j][c]*x[b][c][hw]); mean fp32
// grid 512: jg = blockIdx>>7 (4 groups of 16 j), pix = (blockIdx&127)*256 + tid
__global__ __launch_bounds__(256) void k_comp(const float* __restrict__ x,
                                              const float* __restrict__ b1,
                                              float* __restrict__ ws) {
    const float* w1t = ws + W1T_OFF;
    float* mean = ws + MEAN_OFF;
    unsigned short* cpp = (unsigned short*)(ws + CPP_OFF);
    int jg = blockIdx.x >> 7;                          // uniform
    int pix = ((blockIdx.x & 127) << 8) + threadIdx.x; // 0..32767
    int b = pix >> 12, hw = pix & 4095;
    int h = hw >> 6, wx = hw & 63;
    const float* xp = x + (size_t)b * 256 * 4096 + hw;
    float acc[16];
#pragma unroll
    for (int jj = 0; jj < 16; jj++) acc[jj] = b1[jg * 16 + jj];
    float msum = 0.f;
    for (int c = 0; c < 256; c += 8) {
        float xv[8];
#pragma unroll
        for (int u = 0; u < 8; u++) xv[u] = xp[(size_t)(c + u) * 4096];
#pragma unroll
        for (int u = 0; u < 8; u++) {
            msum += xv[u];
            const float* wp = w1t + (c + u) * 64 + jg * 16;   // uniform -> s_load
#pragma unroll
            for (int jj = 0; jj < 16; jj++) acc[jj] += wp[jj] * xv[u];
        }
    }
    us8 v0, v1;
#pragma unroll
    for (int jj = 0; jj < 8; jj++) { v0[jj] = f2bf(acc[jj]); v1[jj] = f2bf(acc[jj + 8]); }
    unsigned short* dst = cpp + ((size_t)(b * 66 + h + 1) * 66 + (wx + 1)) * 64 + jg * 16;
    *(us8*)dst = v0;
    *(us8*)(dst + 8) = v1;
    if (jg == 0) mean[pix] = msum * (1.f / 256.f);
}

// MFMA GEMM: kern[pixel][o] = A(comp patches) x B(w2b^T), then grad+softmax.
// grid 512 = (b,h); block 384 = 6 waves: wave wid -> (o-tile = wid%3, pixel-half = wid/3).
// A frag: lane l holds A[m = l&15][k = (l>>4)*8 + i]  (8 contiguous j of comp_p)
// B frag: lane l holds B[k = (l>>4)*8 + i][n = l&15]  (8 contiguous k of w2b[n][.])
// D:      lane l holds C[m = (l>>4)*4 + r][n = l&15]  (m89/m91-verified)
__global__ __launch_bounds__(384) void k_mask(const float* __restrict__ b2,
                                              float* __restrict__ ws) {
    const unsigned short* w2b = (const unsigned short*)(ws + W2B_OFF);
    const unsigned short* cpp = (const unsigned short*)(ws + CPP_OFF);
    const float* mean = ws + MEAN_OFF;
    float* mask = ws + MASK_OFF;
    __shared__ float kern[64][49];   // +1 pad: conflict-free epilogue reads

    int b = blockIdx.x >> 6, h = blockIdx.x & 63;
    int t = threadIdx.x;
    int wid = __builtin_amdgcn_readfirstlane(t >> 6);  // 0..5, wave-uniform
    int l = t & 63;
    int o = wid % 3, ph = wid / 3;
    int lm = l & 15, lk = l >> 4;

    // 18 B-fragments held in VGPRs (one o-tile per wave)
    bf8 bfrag[18];
    const unsigned short* bp = w2b + (size_t)(o * 16 + lm) * 576 + lk * 8;
#pragma unroll
    for (int ks = 0; ks < 18; ks++) bfrag[ks] = *(const bf8*)(bp + ks * 32);

    // A base: pixel column lm, j-chunk lk*8, centered at padded (h, 0)
    const unsigned short* abase = cpp + ((size_t)(b * 66 + h) * 66 + lm) * 64 + lk * 8;

#pragma unroll
    for (int hf = 0; hf < 2; hf++) {
        int w0 = (ph * 2 + hf) * 16;
        const unsigned short* ab = abase + w0 * 64;
        f4 acc = {0.f, 0.f, 0.f, 0.f};
#pragma unroll
        for (int ks = 0; ks < 18; ks++) {
            const int s = ks >> 1, jh = ks & 1;
            const int dy = s / 3, dx = s % 3;          // compile-time
            bf8 af = *(const bf8*)(ab + (dy * 66 + dx) * 64 + jh * 32);
            acc = __builtin_amdgcn_mfma_f32_16x16x32_bf16(af, bfrag[ks], acc, 0, 0, 0);
        }
#pragma unroll
        for (int r = 0; r < 4; r++)
            kern[w0 + lk * 4 + r][o * 16 + lm] = acc[r];
    }
    __syncthreads();

    // epilogue: grad guidance + softmax; thread (w, pq) for t < 256
    if (t < 256) {
        int w = t & 63, pq = t >> 6;
        int pixel = (b * 64 + h) * 64 + w;
        float mc = mean[pixel];
        float v[9], mx = -1e30f;
#pragma unroll
        for (int kk = 0; kk < 9; kk++) {
            int y = h + kk / 3 - 1, xw = w + kk % 3 - 1;
            float mv = ((unsigned)y < 64u && (unsigned)xw < 64u)
                           ? mean[(b * 64 + y) * 64 + xw] : 0.f;
            float d = mv - mc;
            float g = 1.f / (d * d + 0.2f);
            v[kk] = g * (kern[w][kk * 4 + pq] + b2[kk * 4 + pq]);
            mx = fmaxf(mx, v[kk]);
        }
        float s = 0.f;
#pragma unroll
        for (int kk = 0; kk < 9; kk++) { v[kk] = __expf(v[kk] - mx); s += v[kk]; }
        float inv = 1.f / s;
        float* mout = mask + (size_t)pixel * 36 + pq * 9;
#pragma unroll
        for (int kk = 0; kk < 9; kk++) mout[kk] = v[kk] * inv;
    }
}

// out[b][c][2h+p][2w+q] = sum_kk x[b][c][h+dy-1][w+dx-1] * mask[b][h][w][p*2+q][kk]
// grid 2048 = (b,h,cq); threads: ow = t&127, cslot = t>>7
__global__ __launch_bounds__(256) void k_out(const float* __restrict__ x,
                                             const float* __restrict__ ws,
                                             float* __restrict__ out) {
    const float* mask = ws + MASK_OFF;
    int bh = blockIdx.x >> 2, cq = blockIdx.x & 3;
    int b = bh >> 6, h = bh & 63;
    int t = threadIdx.x;
    int ow = t & 127, cslot = t >> 7;
    int w = ow >> 1, q = ow & 1;

    const float* mrow = mask + (size_t)((b * 64 + h) * 64 + w) * 36;
    float m0[9], m1[9];
#pragma unroll
    for (int kk = 0; kk < 9; kk++) {
        m0[kk] = mrow[q * 9 + kk];        // p=0 -> pq=q
        m1[kk] = mrow[(2 + q) * 9 + kk];  // p=1 -> pq=2+q
    }

    for (int c = cq * 64 + cslot; c < (cq + 1) * 64; c += 2) {
        const float* xb = x + (size_t)(b * 256 + c) * 4096;
        float p[3][3];
#pragma unroll
        for (int dy = 0; dy < 3; dy++) {
            int y = h + dy - 1;
            bool yok = (unsigned)y < 64u;
#pragma unroll
            for (int dx = 0; dx < 3; dx++) {
                int xx = w + dx - 1;
                p[dy][dx] = (yok && (unsigned)xx < 64u) ? xb[y * 64 + xx] : 0.f;
            }
        }
        float o0 = 0.f, o1 = 0.f;
#pragma unroll
        for (int kk = 0; kk < 9; kk++) {
            float pv = p[kk / 3][kk % 3];
            o0 += pv * m0[kk];
            o1 += pv * m1[kk];
        }
        float* ob = out + ((size_t)(b * 256 + c) * 128 + 2 * h) * 128 + ow;
        ob[0] = o0;     // p=0 row
        ob[128] = o1;   // p=1 row
    }
}

extern "C" void kernel_launch(void* const* d_in, const int* in_sizes, int n_in,
                              void* d_out, int out_size, void* d_ws, size_t ws_size,
                              hipStream_t stream) {
    const float* x  = (const float*)d_in[0];
    const float* w1 = (const float*)d_in[1];
    const float* b1 = (const float*)d_in[2];
    const float* w2 = (const float*)d_in[3];
    const float* b2 = (const float*)d_in[4];
    float* out = (float*)d_out;
    float* ws  = (float*)d_ws;

    k_setup<<<68, 256, 0, stream>>>(w1, w2, ws);
    k_zero<<<1089, 256, 0, stream>>>(ws);
    k_comp<<<512, 256, 0, stream>>>(x, b1, ws);
    k_mask<<<512, 384, 0, stream>>>(b2, ws);
    k_out<<<2048, 256, 0, stream>>>(x, ws, out);
}